// Round 21
// baseline (60.278 us; speedup 1.0000x reference)
//
#include <hip/hip_runtime.h>

// Fused BERT-CRF NER, producer/consumer, SPILL-FREE producers.
// Grid 256 (block=batch), 512 threads (8 waves).
//  Waves 1..7 (producers): rows round-robin (r = pw + 7i), processed in
//    8-row chunks x TWO half-col passes (cols 0-6 with wA, cols 7-12 with wB).
//    Live W <= 84 VGPRs (disjoint wA/wB ranges, reloaded per chunk from L1)
//    -> peak live ~125 < 128: no scratch spill regardless of allocator
//    target (r12 evidence: WRITE_SIZE showed ~23MB spill with 156-reg wreg).
//    Per-col FMA order + DPP tree unchanged -> bit-identical fsT.
//  Wave 0 (consumer): r18/r20 asm chain; spin now contains s_sleep(1) so it
//    doesn't steal issue slots from its SIMD's producer.
//  Phases 2-5 verbatim r20.
// B=256, T=256, H=768, L=13, START=11.
// Outputs (float32): [0..255] max_p/T; [256..65791] path.

#define NEGV (-10000.0f)

#define DPP_ADD(v, ctrl, rmask)                                               \
  v += __int_as_float(__builtin_amdgcn_update_dpp(                            \
      0, __float_as_int(v), (ctrl), (rmask), 0xF, true));

#define DPP_REDUCE64(v)                                                       \
  DPP_ADD(v, 0x111, 0xF)  /* row_shr:1  */                                    \
  DPP_ADD(v, 0x112, 0xF)  /* row_shr:2  */                                    \
  DPP_ADD(v, 0x114, 0xF)  /* row_shr:4  */                                    \
  DPP_ADD(v, 0x118, 0xF)  /* row_shr:8  */                                    \
  DPP_ADD(v, 0x142, 0xA)  /* row_bcast:15 */                                  \
  DPP_ADD(v, 0x143, 0xC)  /* row_bcast:31 */

// k-ascending FMA dozen (bit-identical order to all passing rounds)
#define FMA_ROW(accv, wcol)                                                   \
  accv = fmaf(x0.x, wcol[0],  accv); accv = fmaf(x0.y, wcol[1],  accv);       \
  accv = fmaf(x0.z, wcol[2],  accv); accv = fmaf(x0.w, wcol[3],  accv);       \
  accv = fmaf(x1.x, wcol[4],  accv); accv = fmaf(x1.y, wcol[5],  accv);       \
  accv = fmaf(x1.z, wcol[6],  accv); accv = fmaf(x1.w, wcol[7],  accv);       \
  accv = fmaf(x2.x, wcol[8],  accv); accv = fmaf(x2.y, wcol[9],  accv);       \
  accv = fmaf(x2.z, wcol[10], accv); accv = fmaf(x2.w, wcol[11], accv);

// One Viterbi value-step, hand-scheduled (r18, proven).
__device__ __forceinline__ float vstep_asm(float ld, const float* tr, float ft) {
  float out, v0, v1, v2, v3, v4, v5;
  int s0, s1, s2, s3, s4, s5;
  asm("v_readlane_b32 %[s0], %[ld], 0\n\t"
      "v_readlane_b32 %[s1], %[ld], 1\n\t"
      "v_readlane_b32 %[s2], %[ld], 2\n\t"
      "v_readlane_b32 %[s3], %[ld], 3\n\t"
      "v_readlane_b32 %[s4], %[ld], 4\n\t"
      "v_readlane_b32 %[s5], %[ld], 5\n\t"
      "v_add_f32 %[v0], %[s0], %[t0]\n\t"
      "v_add_f32 %[v1], %[s1], %[t1]\n\t"
      "v_add_f32 %[v2], %[s2], %[t2]\n\t"
      "v_readlane_b32 %[s0], %[ld], 6\n\t"
      "v_readlane_b32 %[s1], %[ld], 7\n\t"
      "v_readlane_b32 %[s2], %[ld], 8\n\t"
      "v_add_f32 %[v3], %[s3], %[t3]\n\t"
      "v_add_f32 %[v4], %[s4], %[t4]\n\t"
      "v_add_f32 %[v5], %[s5], %[t5]\n\t"
      "v_max3_f32 %[v0], %[v0], %[v1], %[v2]\n\t"   // m0
      "v_max3_f32 %[v3], %[v3], %[v4], %[v5]\n\t"   // m1
      "v_readlane_b32 %[s3], %[ld], 9\n\t"
      "v_readlane_b32 %[s4], %[ld], 10\n\t"
      "v_readlane_b32 %[s5], %[ld], 11\n\t"
      "v_add_f32 %[v1], %[s0], %[t6]\n\t"
      "v_add_f32 %[v2], %[s1], %[t7]\n\t"
      "v_add_f32 %[v4], %[s2], %[t8]\n\t"
      "v_readlane_b32 %[s0], %[ld], 12\n\t"
      "v_max3_f32 %[v1], %[v1], %[v2], %[v4]\n\t"   // m2
      "v_add_f32 %[v2], %[s3], %[t9]\n\t"
      "v_add_f32 %[v4], %[s4], %[t10]\n\t"
      "v_add_f32 %[v5], %[s5], %[t11]\n\t"
      "v_max3_f32 %[v2], %[v2], %[v4], %[v5]\n\t"   // m3
      "v_add_f32 %[v4], %[s0], %[t12]\n\t"          // c12
      "v_max3_f32 %[v0], %[v0], %[v3], %[v1]\n\t"   // max(m0,m1,m2)
      "v_max3_f32 %[v0], %[v0], %[v2], %[v4]\n\t"   // max(.., m3, c12)
      "v_add_f32 %[o], %[v0], %[ft]"
      : [o] "=&v"(out),
        [s0] "=&s"(s0), [s1] "=&s"(s1), [s2] "=&s"(s2),
        [s3] "=&s"(s3), [s4] "=&s"(s4), [s5] "=&s"(s5),
        [v0] "=&v"(v0), [v1] "=&v"(v1), [v2] "=&v"(v2),
        [v3] "=&v"(v3), [v4] "=&v"(v4), [v5] "=&v"(v5)
      : [ld] "v"(ld), [ft] "v"(ft),
        [t0] "v"(tr[0]), [t1] "v"(tr[1]), [t2] "v"(tr[2]), [t3] "v"(tr[3]),
        [t4] "v"(tr[4]), [t5] "v"(tr[5]), [t6] "v"(tr[6]), [t7] "v"(tr[7]),
        [t8] "v"(tr[8]), [t9] "v"(tr[9]), [t10] "v"(tr[10]),
        [t11] "v"(tr[11]), [t12] "v"(tr[12]));
  return out;
}

__global__ __launch_bounds__(512)
__attribute__((amdgpu_waves_per_eu(2, 2)))
void fused_kernel(
    const float* __restrict__ X,      // [65536, 768]
    const float* __restrict__ W,      // [13, 768]
    const float* __restrict__ bias,   // [13]
    const float* __restrict__ trans,  // [13,13]
    float* __restrict__ out)          // [256 + 65536]
{
  __shared__ float fsT[13 * 260];          // feats transposed [to][t]
  __shared__ float lds_ld[256 * 16];       // ld_t[to]
  __shared__ float trL[176];               // trans (169 used)
  __shared__ unsigned char psi[256 * 16];  // psi[t][to]
  __shared__ unsigned char Mm[256];
  __shared__ unsigned char bnd[16];
  __shared__ unsigned char path[256];
  __shared__ int flags[256];               // per-row ready flags

  const int tid = threadIdx.x;
  const int w = tid >> 6, l = tid & 63;
  const int b = blockIdx.x;

  if (tid < 169) trL[tid] = trans[tid];
  if (tid < 256) flags[tid] = 0;
  __syncthreads();

  if (w == 0) {
    // ================== CONSUMER: Viterbi chain (lanes 0-15) ================
    if (l < 16) {
      const int lane = l;
      float tr[13];
      #pragma unroll
      for (int f = 0; f < 13; ++f)
        tr[f] = (lane < 13) ? trans[lane * 13 + f] : -1.0e30f;

      const int toc = (lane < 13) ? lane : 0;
      const float* frow = &fsT[toc * 260];
      volatile int* vf = flags;

      float ld = (lane == 11) ? 0.0f : NEGV;  // START = 11
      lds_ld[lane] = ld;                      // t = 0

      #pragma unroll 1
      for (int g = 0; g < 16; ++g) {
        // wait until all 16 rows of this chunk are produced; sleep so the
        // spin doesn't steal issue slots from SIMD0's producer wave
        while (!__all(vf[g * 16 + lane] != 0)) {
          __builtin_amdgcn_s_sleep(1);
        }
        asm volatile("" ::: "memory");

        float4 F[4];
        #pragma unroll
        for (int q = 0; q < 4; ++q)
          F[q] = *reinterpret_cast<const float4*>(frow + g * 16 + 4 * q);

        if (g == 0) {
          #pragma unroll
          for (int k = 1; k < 16; ++k) {
            const float4 fq = F[k >> 2];
            const float ftv = ((k & 3) == 0) ? fq.x : ((k & 3) == 1) ? fq.y
                             : ((k & 3) == 2) ? fq.z : fq.w;
            ld = vstep_asm(ld, tr, ftv);
            lds_ld[k * 16 + lane] = ld;
          }
        } else {
          #pragma unroll
          for (int k = 0; k < 16; ++k) {
            const int t = g * 16 + k;
            const float4 fq = F[k >> 2];
            const float ftv = ((k & 3) == 0) ? fq.x : ((k & 3) == 1) ? fq.y
                             : ((k & 3) == 2) ? fq.z : fq.w;
            ld = vstep_asm(ld, tr, ftv);
            lds_ld[t * 16 + lane] = ld;
          }
        }
      }
    }
  } else {
    // ============ PRODUCERS (waves 1-7): spill-free col-split feats =========
    const int pw = w - 1;                    // 0..6
    const int imax = (pw < 4) ? 37 : 36;     // rows r = pw + 7i
    const float* Xb = X + (long)b * 196608 + 4 * l;

    float bs[13];
    #pragma unroll
    for (int c = 0; c < 13; ++c) bs[c] = bias[c];

    #pragma unroll 1
    for (int ch = 0; ch < 5; ++ch) {         // 8-iteration chunks
      const int i0 = ch * 8;
      if (i0 >= imax) break;                 // wave-uniform

      // ---------- pass A: cols 0..6 (wA live: 84 regs) ----------
      {
        float wA[7][12];
        #pragma unroll
        for (int col = 0; col < 7; ++col) {
          #pragma unroll
          for (int j = 0; j < 3; ++j) {
            float4 v = *reinterpret_cast<const float4*>(
                W + col * 768 + 256 * j + 4 * l);
            wA[col][4*j+0] = v.x; wA[col][4*j+1] = v.y;
            wA[col][4*j+2] = v.z; wA[col][4*j+3] = v.w;
          }
        }
        float4 x0, x1, x2, n0, n1, n2;
        {
          const float* xr = Xb + (pw + 7 * i0) * 768;
          x0 = *reinterpret_cast<const float4*>(xr);
          x1 = *reinterpret_cast<const float4*>(xr + 256);
          x2 = *reinterpret_cast<const float4*>(xr + 512);
        }
        #pragma unroll
        for (int j = 0; j < 8; ++j) {
          const int i = i0 + j;
          if (i < imax) {
            {
              const int inx = (i + 1 < imax) ? i + 1 : i;   // clamped prefetch
              const float* xr = Xb + (pw + 7 * inx) * 768;
              n0 = *reinterpret_cast<const float4*>(xr);
              n1 = *reinterpret_cast<const float4*>(xr + 256);
              n2 = *reinterpret_cast<const float4*>(xr + 512);
            }
            float acc[7];
            #pragma unroll
            for (int c = 0; c < 7; ++c) acc[c] = 0.0f;
            #pragma unroll
            for (int c = 0; c < 7; ++c) { FMA_ROW(acc[c], wA[c]) }
            #pragma unroll
            for (int c = 0; c < 7; ++c) { DPP_REDUCE64(acc[c]) }
            if (l == 63) {
              const int r = pw + 7 * i;
              #pragma unroll
              for (int c = 0; c < 7; ++c)
                fsT[c * 260 + r] = acc[c] + bs[c];
            }
            x0 = n0; x1 = n1; x2 = n2;
          }
        }
      }

      // ---------- pass B: cols 7..12 (wB live: 72 regs) ----------
      {
        float wB[6][12];
        #pragma unroll
        for (int col = 0; col < 6; ++col) {
          #pragma unroll
          for (int j = 0; j < 3; ++j) {
            float4 v = *reinterpret_cast<const float4*>(
                W + (7 + col) * 768 + 256 * j + 4 * l);
            wB[col][4*j+0] = v.x; wB[col][4*j+1] = v.y;
            wB[col][4*j+2] = v.z; wB[col][4*j+3] = v.w;
          }
        }
        float4 x0, x1, x2, n0, n1, n2;
        {
          const float* xr = Xb + (pw + 7 * i0) * 768;   // L1-hot (pass A)
          x0 = *reinterpret_cast<const float4*>(xr);
          x1 = *reinterpret_cast<const float4*>(xr + 256);
          x2 = *reinterpret_cast<const float4*>(xr + 512);
        }
        #pragma unroll
        for (int j = 0; j < 8; ++j) {
          const int i = i0 + j;
          if (i < imax) {
            {
              const int inx = (i + 1 < imax) ? i + 1 : i;
              const float* xr = Xb + (pw + 7 * inx) * 768;
              n0 = *reinterpret_cast<const float4*>(xr);
              n1 = *reinterpret_cast<const float4*>(xr + 256);
              n2 = *reinterpret_cast<const float4*>(xr + 512);
            }
            float acc[6];
            #pragma unroll
            for (int c = 0; c < 6; ++c) acc[c] = 0.0f;
            #pragma unroll
            for (int c = 0; c < 6; ++c) { FMA_ROW(acc[c], wB[c]) }
            #pragma unroll
            for (int c = 0; c < 6; ++c) { DPP_REDUCE64(acc[c]) }
            if (l == 63) {
              const int r = pw + 7 * i;
              #pragma unroll
              for (int c = 0; c < 6; ++c)
                fsT[(7 + c) * 260 + r] = acc[c] + bs[7 + c];
              asm volatile("s_waitcnt lgkmcnt(0)" ::: "memory");
              flags[r] = 1;               // row complete (A writes drained too)
            }
            x0 = n0; x1 = n1; x2 = n2;
          }
        }
      }
    }
  }
  __syncthreads();

  // ================== phases 2-5 (verbatim r20, 512 threads) ================
  {
    const int to = tid & 15, dtt = tid >> 4;   // dtt = 0..31
    if (to < 13) {
      float trr[13];
      #pragma unroll
      for (int f = 0; f < 13; ++f) trr[f] = trL[to * 13 + f];
      for (int t = (dtt == 0 ? 32 : dtt); t < 256; t += 32) {
        const float* lp = &lds_ld[(t - 1) * 16];
        float4 l0 = *reinterpret_cast<const float4*>(lp);
        float4 l1 = *reinterpret_cast<const float4*>(lp + 4);
        float4 l2 = *reinterpret_cast<const float4*>(lp + 8);
        float4 l3 = *reinterpret_cast<const float4*>(lp + 12);
        float c[13] = {trr[0] + l0.x,  trr[1] + l0.y,  trr[2] + l0.z,
                       trr[3] + l0.w,  trr[4] + l1.x,  trr[5] + l1.y,
                       trr[6] + l1.z,  trr[7] + l1.w,  trr[8] + l2.x,
                       trr[9] + l2.y,  trr[10] + l2.z, trr[11] + l2.w,
                       trr[12] + l3.x};
        float best = c[0]; int bf = 0;
        #pragma unroll
        for (int f = 1; f < 13; ++f) {
          bool gt = c[f] > best;              // strict >: first index wins
          best = gt ? c[f] : best;
          bf   = gt ? f : bf;
        }
        psi[t * 16 + to] = (unsigned char)bf;
      }
    }
  }
  __syncthreads();

  if (tid < 256) {
    const int sS = tid & 15, g = tid >> 4;
    if (sS < 13) {
      int cur = sS;
      const int tLo = (g == 0) ? 1 : g * 16;
      for (int t = g * 16 + 15; t >= tLo; --t)
        cur = psi[t * 16 + cur];
      Mm[g * 16 + sS] = (unsigned char)cur;
    }
  }
  __syncthreads();

  if (tid == 0) {
    const float* lf = &lds_ld[255 * 16];
    float m = lf[0]; int last = 0;
    #pragma unroll
    for (int i = 1; i < 13; ++i)
      if (lf[i] > m) { m = lf[i]; last = i; }   // strict >: first index
    float ssum = 0.0f;
    #pragma unroll
    for (int i = 0; i < 13; ++i) ssum += expf(lf[i] - m);
    out[b] = 1.0f / (256.0f * ssum);            // max(softmax)/T

    int cur = last;
    bnd[15] = (unsigned char)cur;
    #pragma unroll
    for (int cc = 15; cc >= 1; --cc) {
      cur = Mm[cc * 16 + cur];
      bnd[cc - 1] = (unsigned char)cur;
    }
  }
  __syncthreads();

  if (tid < 16) {
    int cur = bnd[tid];
    const int tHi = tid * 16 + 15;
    path[tHi] = (unsigned char)cur;
    const int tLo = (tid == 0) ? 1 : tid * 16;
    for (int t = tHi; t >= tLo; --t) {
      cur = psi[t * 16 + cur];
      path[t - 1] = (unsigned char)cur;
    }
  }
  __syncthreads();

  if (tid < 256)
    out[256 + (long)b * 256 + tid] = (float)path[tid];
}

// ------------------------------------------------------------------ launch --
extern "C" void kernel_launch(void* const* d_in, const int* in_sizes, int n_in,
                              void* d_out, int out_size, void* d_ws, size_t ws_size,
                              hipStream_t stream) {
  const float* X     = (const float*)d_in[0];
  const float* W     = (const float*)d_in[1];
  const float* bias  = (const float*)d_in[2];
  const float* trans = (const float*)d_in[3];
  float* out = (float*)d_out;

  fused_kernel<<<256, 512, 0, stream>>>(X, W, bias, trans, out);
}